// Round 6
// baseline (261.848 us; speedup 1.0000x reference)
//
#include <hip/hip_runtime.h>

// YOLO loss, B=16384, 7x7 grid, pred=30ch f32, targ=25ch f32 -> scalar sum.
//
// Rounds 2-5 post-mortem: every LDS-staged variant is latency-bound at
// 67-115 us with both pipes <17% busy -- the 14 KB/tile LDS footprint caps
// residency at 5-10 waves/CU, and neither barriers (r2/r3) nor a 2-deep
// counted-vmcnt pipeline (r5) can cover loaded-memory latency at that TLP.
//
// This round: NO LDS, NO barriers. 4 cells per thread makes both arrays
// perfectly float4-aligned per lane (pred 480 B = 30 f4, targ 400 B = 25 f4,
// bases 480i/400i = 0 mod 16). Per-lane contiguous f4 streams; every line
// fully consumed; occupancy VGPR-limited (~12 waves/CU at launch_bounds
// (256,3)) -> latency hidden by plain TLP like m238's 86%-BW RMSNorm.

#define TPB  256
#define GRID 784          // 784 * 256 threads * 4 cells = 802816 cells exact

__device__ __forceinline__ float cell_loss(const float* pv, const float* tv)
{
    float c1 = pv[4], c2 = pv[9], cc = tv[4];
    bool present = (cc == 1.0f);
    bool resp1   = (c1 > c2);

    float d1 = c1 - cc, d2 = c2 - cc;
    float obj = present ? (resp1 ? d1 * d1 : d2 * d2)
                        : 0.5f * (c1 * c1 + c2 * c2);

    float cls = 0.0f;
    #pragma unroll
    for (int k = 0; k < 20; ++k) {
        float d = pv[10 + k] - tv[5 + k];
        cls += d * d;
    }

    float pc0 = resp1 ? pv[0] : pv[5];
    float pc1 = resp1 ? pv[1] : pv[6];
    float ph0 = resp1 ? pv[2] : pv[7];
    float ph1 = resp1 ? pv[3] : pv[8];
    float b0 = pc0 - tv[0];
    float b1 = pc1 - tv[1];
    float s0 = sqrtf(ph0) - sqrtf(tv[2]);
    float s1 = sqrtf(ph1) - sqrtf(tv[3]);
    float box = b0 * b0 + b1 * b1 + s0 * s0 + s1 * s1;

    return obj + (present ? (cls + 5.0f * box) : 0.0f);
}

__global__ __launch_bounds__(TPB, 3) void yolo_loss_kernel(
    const float* __restrict__ pred,
    const float* __restrict__ targ,
    float* __restrict__ out)
{
    const int i = blockIdx.x * TPB + threadIdx.x;          // 0 .. 200703
    const float4* gp = (const float4*)pred + (size_t)i * 30;  // 480 B, 16-al
    const float4* gt = (const float4*)targ + (size_t)i * 25;  // 400 B, 16-al

    float loss = 0.0f;

    // ---- pair 0: cells 0,1  (pred f4 0..14 = floats 0..59;
    //                          targ f4 0..12 = floats 0..51 >= cells' 0..49) ----
    {
        float4 P[15], T[13];
        #pragma unroll
        for (int r = 0; r < 15; ++r) P[r] = gp[r];
        #pragma unroll
        for (int r = 0; r < 13; ++r) T[r] = gt[r];
        const float* pv = (const float*)P;
        const float* tv = (const float*)T;      // all indices constant post-unroll
        loss += cell_loss(pv,      tv);         // cell 0
        loss += cell_loss(pv + 30, tv + 25);    // cell 1
    }
    // ---- pair 1: cells 2,3  (pred f4 15..29 = floats 60..119;
    //                          targ f4 12..24 = floats 48..99 >= cells' 50..99) ----
    {
        float4 P[15], T[13];
        #pragma unroll
        for (int r = 0; r < 15; ++r) P[r] = gp[15 + r];
        #pragma unroll
        for (int r = 0; r < 13; ++r) T[r] = gt[12 + r];   // float4 #12 re-read (1 instr)
        const float* pv = (const float*)P;
        const float* tv = (const float*)T;      // cell floats start at tv+2
        loss += cell_loss(pv,      tv + 2);     // cell 2
        loss += cell_loss(pv + 30, tv + 27);    // cell 3
    }

    // ---- wave-64 reduce -> one atomic per wave (no LDS, no barrier) ----
    #pragma unroll
    for (int off = 32; off > 0; off >>= 1)
        loss += __shfl_down(loss, off);
    if ((threadIdx.x & 63) == 0)
        atomicAdd(out, loss);
}

extern "C" void kernel_launch(void* const* d_in, const int* in_sizes, int n_in,
                              void* d_out, int out_size, void* d_ws, size_t ws_size,
                              hipStream_t stream)
{
    const float* pred = (const float*)d_in[0];
    const float* targ = (const float*)d_in[1];
    float* out = (float*)d_out;

    // harness poisons d_out with 0xAA before every launch -> zero it (capture-safe)
    hipMemsetAsync(out, 0, sizeof(float), stream);

    hipLaunchKernelGGL(yolo_loss_kernel, dim3(GRID), dim3(TPB), 0, stream,
                       pred, targ, out);
}

// Round 7
// 193.299 us; speedup vs baseline: 1.3546x; 1.3546x over previous
//
#include <hip/hip_runtime.h>

// YOLO loss, B=16384, 7x7 grid, pred=30ch f32, targ=25ch f32 -> scalar sum.
//
// Round-6 postmortem: (a) float4 arrays + reinterpret casts spilled to scratch
// (WRITE_SIZE 44 MB); (b) cross-round cycle accounting shows every
// global_load_lds-staged tile cost ~#instr x 700-900 cy per wave -> the
// LDS-DMA path appears to serialize intra-wave (no MLP). Normal
// global_load->VGPR pipelines (m135: 8 loads drain in ~330 cy).
//
// This round: register-staged LDS transpose, single-wave blocks, no barriers.
//   15 independent global_load_dwordx4 (one latency for the whole batch)
//   -> 15 linear ds_write_b128 (LDS = verbatim tile copy, no scatter math)
//   -> strided LDS reads, 1 lane = 1 cell.
// 14 KB LDS/block -> 11 resident blocks/CU (2x r3's waves). 12544 blocks;
// atomics spread over 128 ws slots (128 B apart), tiny finish kernel sums.

#define TPB         64
#define NTILES      12544          // 802816 / 64 cells
#define P_F4        480            // pred float4 per tile (64*30/4)
#define T_F4        400            // targ float4 per tile (64*25/4)
#define SLOTS       128
#define SLOT_STRIDE 32             // floats -> 128 B apart
#define WS_NEED     (SLOTS * SLOT_STRIDE * 4)

__global__ __launch_bounds__(TPB) void yolo_main(
    const float* __restrict__ pred,
    const float* __restrict__ targ,
    float* __restrict__ acc,       // SLOTS spread slots (or out in fallback)
    int slot_mask, int slot_stride)
{
    __shared__ float4 sp4[P_F4];   // 7680 B
    __shared__ float4 st4[T_F4];   // 6400 B   (14080 B total)

    const int L = threadIdx.x;
    const int t = blockIdx.x;

    const float4* gp = (const float4*)pred + (size_t)t * P_F4;
    const float4* gt = (const float4*)targ + (size_t)t * T_F4;

    // ---- issue all 15 loads to independent VGPRs (pipelined in flight) ----
    float4 P0 = gp[L];
    float4 P1 = gp[ 64 + L];
    float4 P2 = gp[128 + L];
    float4 P3 = gp[192 + L];
    float4 P4 = gp[256 + L];
    float4 P5 = gp[320 + L];
    float4 P6 = gp[384 + L];
    float4 T0 = gt[L];
    float4 T1 = gt[ 64 + L];
    float4 T2 = gt[128 + L];
    float4 T3 = gt[192 + L];
    float4 T4 = gt[256 + L];
    float4 T5 = gt[320 + L];
    float4 P7, T6;
    if (L < 32) P7 = gp[448 + L];
    if (L < 16) T6 = gt[384 + L];

    // ---- linear LDS copy (compiler inserts minimal vmcnt before each) ----
    sp4[L] = P0;  sp4[ 64 + L] = P1;  sp4[128 + L] = P2;  sp4[192 + L] = P3;
    sp4[256 + L] = P4;  sp4[320 + L] = P5;  sp4[384 + L] = P6;
    st4[L] = T0;  st4[ 64 + L] = T1;  st4[128 + L] = T2;  st4[192 + L] = T3;
    st4[256 + L] = T4;  st4[320 + L] = T5;
    if (L < 32) sp4[448 + L] = P7;
    if (L < 16) st4[384 + L] = T6;
    // single wave owns the tile: same-wave LDS RAW handled via lgkmcnt,
    // no __syncthreads anywhere.

    // ---- per-cell compute: lane L = cell L ----
    const float* sp = (const float*)sp4;
    const float* st = (const float*)st4;

    const float2* pv2 = (const float2*)(sp + L * 30);  // 120 B stride, 8B-al
    float pv[30];
    #pragma unroll
    for (int i = 0; i < 15; ++i) {
        float2 v = pv2[i];
        pv[2*i] = v.x; pv[2*i+1] = v.y;
    }
    const float* tvp = st + L * 25;                    // 100 B stride
    float tv[25];
    #pragma unroll
    for (int i = 0; i < 25; ++i) tv[i] = tvp[i];

    float c1 = pv[4], c2 = pv[9], cc = tv[4];
    bool present = (cc == 1.0f);
    bool resp1   = (c1 > c2);

    float d1 = c1 - cc, d2 = c2 - cc;
    float obj = present ? (resp1 ? d1 * d1 : d2 * d2)
                        : 0.5f * (c1 * c1 + c2 * c2);

    float cls = 0.0f;
    #pragma unroll
    for (int k = 0; k < 20; ++k) {
        float d = pv[10 + k] - tv[5 + k];
        cls += d * d;
    }

    float pc0 = resp1 ? pv[0] : pv[5];
    float pc1 = resp1 ? pv[1] : pv[6];
    float ph0 = resp1 ? pv[2] : pv[7];
    float ph1 = resp1 ? pv[3] : pv[8];
    float b0 = pc0 - tv[0];
    float b1 = pc1 - tv[1];
    float s0 = sqrtf(ph0) - sqrtf(tv[2]);
    float s1 = sqrtf(ph1) - sqrtf(tv[3]);
    float box = b0 * b0 + b1 * b1 + s0 * s0 + s1 * s1;

    float loss = obj + (present ? (cls + 5.0f * box) : 0.0f);

    // ---- wave reduce -> one spread atomic per block ----
    #pragma unroll
    for (int off = 32; off > 0; off >>= 1)
        loss += __shfl_down(loss, off);
    if (L == 0)
        atomicAdd(&acc[(t & slot_mask) * slot_stride], loss);
}

__global__ __launch_bounds__(64) void yolo_finish(
    const float* __restrict__ ws, float* __restrict__ out)
{
    const int L = threadIdx.x;
    float s = ws[L * SLOT_STRIDE] + ws[(64 + L) * SLOT_STRIDE];
    #pragma unroll
    for (int off = 32; off > 0; off >>= 1)
        s += __shfl_down(s, off);
    if (L == 0) out[0] = s;
}

extern "C" void kernel_launch(void* const* d_in, const int* in_sizes, int n_in,
                              void* d_out, int out_size, void* d_ws, size_t ws_size,
                              hipStream_t stream)
{
    const float* pred = (const float*)d_in[0];
    const float* targ = (const float*)d_in[1];
    float* out = (float*)d_out;
    float* ws  = (float*)d_ws;

    if (ws_size >= (size_t)WS_NEED) {
        hipMemsetAsync(ws, 0, WS_NEED, stream);
        hipLaunchKernelGGL(yolo_main, dim3(NTILES), dim3(TPB), 0, stream,
                           pred, targ, ws, SLOTS - 1, SLOT_STRIDE);
        hipLaunchKernelGGL(yolo_finish, dim3(1), dim3(64), 0, stream, ws, out);
    } else {
        // fallback: accumulate directly into out
        hipMemsetAsync(out, 0, sizeof(float), stream);
        hipLaunchKernelGGL(yolo_main, dim3(NTILES), dim3(TPB), 0, stream,
                           pred, targ, out, 0, 0);
    }
}